// Round 4
// baseline (342.854 us; speedup 1.0000x reference)
//
#include <hip/hip_runtime.h>
#include <hip/hip_bf16.h>

#define RADIUS 20
#define KSIZE  41
#define ALPHA_F 50.0f
#define TY     8
#define WID    512
#define HEI    512
#define PW     (WID + 2 * RADIUS)   // 552 floats per padded LDS row

// Normalized Gaussian taps, sigma=5, radius=20: w[t]=exp(-0.5*((t-20)/5)^2)/S,
// S = 12.53263858. Baked literals; fully-unrolled loops fold these to constants.
__device__ constexpr float G[KSIZE] = {
    2.6770e-05f, 5.8390e-05f, 1.22380e-04f, 2.46460e-04f, 4.76840e-04f,
    8.86410e-04f, 1.583160e-03f, 2.716710e-03f, 4.479090e-03f, 7.095210e-03f,
    1.0798630e-02f, 1.5790680e-02f, 2.2185070e-02f, 2.9946720e-02f, 3.8838800e-02f,
    4.8396120e-02f, 5.7940680e-02f, 6.6647650e-02f, 7.3657040e-02f, 7.8211730e-02f,
    7.9791720e-02f,
    7.8211730e-02f, 7.3657040e-02f, 6.6647650e-02f, 5.7940680e-02f, 4.8396120e-02f,
    3.8838800e-02f, 2.9946720e-02f, 2.2185070e-02f, 1.5790680e-02f, 1.0798630e-02f,
    7.095210e-03f, 4.479090e-03f, 2.716710e-03f, 1.583160e-03f, 8.86410e-04f,
    4.76840e-04f, 2.46460e-04f, 1.22380e-04f, 5.8390e-05f, 2.6770e-05f
};

__device__ __forceinline__ int refl(int i, int n) {
    // scipy 'reflect' (edge included); exact for i in [-n, 2n-1]
    i = (i < 0) ? (-1 - i) : i;
    i = (i >= n) ? (2 * n - 1 - i) : i;
    return i;
}
__device__ __forceinline__ int clampi(int i, int n) {
    return (i < 0) ? 0 : ((i >= n) ? n - 1 : i);
}
__device__ __forceinline__ float h2f(unsigned short h) {
    unsigned int u = ((unsigned int)h) << 16;
    float f;
    __builtin_memcpy(&f, &u, 4);
    return f;
}
__device__ __forceinline__ float ldf(const float* p) { return *p; }
__device__ __forceinline__ float ldf(const __hip_bfloat16* p) { return __bfloat162float(*p); }

// TR = dtype of rand fields, TX = dtype of image x. Output fp32 (reference dtype).
// phase 1: vertical 41-tap blur of (2*r-1), accumulator-transposed -> LDS (+-20 reflected col halo)
// phase 2: horizontal 41-tap blur (*ALPHA) + bilinear warp of x -> fp32 out
template <typename TR, typename TX>
__device__ __forceinline__ void elastic_body(
    const TX* __restrict__ xin, const TR* __restrict__ rdx, const TR* __restrict__ rdy,
    float* __restrict__ outp,
    float (&sdx)[TY][PW], float (&sdy)[TY][PW]) {

    const int tid = threadIdx.x;                 // 0..511 == column in phase 1
    const int y0  = blockIdx.x * TY;
    const int b   = blockIdx.y;
    const size_t base = (size_t)b * (HEI * WID);

    // ---------------- phase 1 ----------------
    {
        float ax[TY], ay[TY];
        #pragma unroll
        for (int o = 0; o < TY; ++o) { ax[o] = 0.f; ay[o] = 0.f; }

        const TR* px = rdx + base + tid;
        const TR* py = rdy + base + tid;

        #pragma unroll
        for (int r = 0; r < TY + 2 * RADIUS; ++r) {      // 48 input rows
            const int gy = refl(y0 - RADIUS + r, HEI);
            const float vx = ldf(px + (size_t)gy * WID);
            const float vy = ldf(py + (size_t)gy * WID);
            #pragma unroll
            for (int o = 0; o < TY; ++o) {
                const int t = r - o;                      // static after unroll
                if (t >= 0 && t < KSIZE) {
                    ax[o] = fmaf(G[t], vx, ax[o]);
                    ay[o] = fmaf(G[t], vy, ay[o]);
                }
            }
        }

        #pragma unroll
        for (int o = 0; o < TY; ++o) {
            const float sx = 2.f * ax[o] - 1.f;           // affine commutes with blur (sum G = 1)
            const float sy = 2.f * ay[o] - 1.f;
            sdx[o][RADIUS + tid] = sx;
            sdy[o][RADIUS + tid] = sy;
            if (tid < RADIUS) {                           // col -1-j reflects to col j
                sdx[o][RADIUS - 1 - tid] = sx;
                sdy[o][RADIUS - 1 - tid] = sy;
            }
            if (tid >= WID - RADIUS) {                    // col W+j reflects to col W-1-j
                sdx[o][RADIUS + 2 * WID - 1 - tid] = sx;
                sdy[o][RADIUS + 2 * WID - 1 - tid] = sy;
            }
        }
    }
    __syncthreads();

    // ---------------- phase 2 ----------------
    const int c4 = tid & 127;          // float4 index -> cols 4*c4..4*c4+3
    const int rg = tid >> 7;           // 0..3 (wave-uniform)
    const TX* img = xin + base;

    #pragma unroll
    for (int i = 0; i < 2; ++i) {
        const int o  = rg + 4 * i;     // rows 0..7
        const int gy = y0 + o;

        float dxv[4] = {0.f, 0.f, 0.f, 0.f};
        float dyv[4] = {0.f, 0.f, 0.f, 0.f};

        {   // 11 aligned float4 LDS reads -> 44-float window, then 41-tap FMA x4 cols
            float w[44];
            const float4* rp = (const float4*)(&sdx[o][0]);
            #pragma unroll
            for (int q = 0; q < 11; ++q) {
                const float4 v = rp[c4 + q];
                w[4 * q + 0] = v.x; w[4 * q + 1] = v.y;
                w[4 * q + 2] = v.z; w[4 * q + 3] = v.w;
            }
            #pragma unroll
            for (int t = 0; t < KSIZE; ++t) {
                const float g = G[t];
                #pragma unroll
                for (int j = 0; j < 4; ++j) dxv[j] = fmaf(g, w[t + j], dxv[j]);
            }
        }
        {
            float w[44];
            const float4* rp = (const float4*)(&sdy[o][0]);
            #pragma unroll
            for (int q = 0; q < 11; ++q) {
                const float4 v = rp[c4 + q];
                w[4 * q + 0] = v.x; w[4 * q + 1] = v.y;
                w[4 * q + 2] = v.z; w[4 * q + 3] = v.w;
            }
            #pragma unroll
            for (int t = 0; t < KSIZE; ++t) {
                const float g = G[t];
                #pragma unroll
                for (int j = 0; j < 4; ++j) dyv[j] = fmaf(g, w[t + j], dyv[j]);
            }
        }

        float st[4];
        #pragma unroll
        for (int j = 0; j < 4; ++j) {
            const int col = 4 * c4 + j;
            float xx = (float)col + dxv[j] * ALPHA_F;
            float yy = (float)gy  + dyv[j] * ALPHA_F;
            // safety clamp: legit range is [-51, 562]; also neutralizes NaN/inf
            xx = fminf(fmaxf(xx, -2048.f), 2048.f);
            yy = fminf(fmaxf(yy, -2048.f), 2048.f);
            const float x0f = floorf(xx), y0f = floorf(yy);
            const float wx = xx - x0f, wy = yy - y0f;
            const int x0 = (int)x0f, yb = (int)y0f;
            const int x0r = clampi(refl(x0, WID), WID);
            const int x1r = clampi(refl(x0 + 1, WID), WID);
            const int y0r = clampi(refl(yb, HEI), HEI);
            const int y1r = clampi(refl(yb + 1, HEI), HEI);

            const float v00 = ldf(img + (size_t)y0r * WID + x0r);
            const float v01 = ldf(img + (size_t)y0r * WID + x1r);
            const float v10 = ldf(img + (size_t)y1r * WID + x0r);
            const float v11 = ldf(img + (size_t)y1r * WID + x1r);

            st[j] = v00 * (1.f - wy) * (1.f - wx) + v01 * (1.f - wy) * wx
                  + v10 * wy * (1.f - wx) + v11 * wy * wx;
        }

        float4 pack;
        pack.x = st[0]; pack.y = st[1]; pack.z = st[2]; pack.w = st[3];
        *reinterpret_cast<float4*>(outp + base + (size_t)gy * WID + 4 * c4) = pack;
    }
}

__global__ __launch_bounds__(512) void elastic_kernel(
    const void* __restrict__ xin_v, const void* __restrict__ rdx_v,
    const void* __restrict__ rdy_v, float* __restrict__ outp) {

    __shared__ float sdx[TY][PW];   // 2 * 8 * 552 * 4B = 34.5 KB total
    __shared__ float sdy[TY][PW];
    __shared__ int flags[2];

    const int tid = threadIdx.x;

    // -------- on-device dtype detection (wave-uniform result, ~free) --------
    // Interpret first 512 words of each input as packed bf16 pairs. For real
    // fp32 data the low halfwords have random exponents -> range checks fail
    // with probability ~1 - 0.25^512. NaN compares false -> classified fp32.
    if (tid == 0) { flags[0] = 1; flags[1] = 1; }
    __syncthreads();
    {
        const unsigned int wr = ((const unsigned int*)rdx_v)[tid];  // 2 KB, in-bounds either dtype
        const unsigned int wx = ((const unsigned int*)xin_v)[tid];
        const float r0 = h2f((unsigned short)(wr & 0xffffu));
        const float r1 = h2f((unsigned short)(wr >> 16));
        const float q0 = h2f((unsigned short)(wx & 0xffffu));
        const float q1 = h2f((unsigned short)(wx >> 16));
        // uniforms in [0,1) may round up to exactly 1.0 in bf16 -> allow <1.5
        const bool rb = (r0 >= 0.f) && (r0 < 1.5f) && (r1 >= 0.f) && (r1 < 1.5f);
        const bool xb = (fabsf(q0) < 32.f) && (fabsf(q1) < 32.f);   // normals, |v| <~ 5.6
        if (!rb) atomicAnd(&flags[0], 0);
        if (!xb) atomicAnd(&flags[1], 0);
    }
    __syncthreads();
    const bool rand_bf = (flags[0] != 0);
    const bool x_bf    = (flags[1] != 0);

    if (rand_bf) {
        if (x_bf) elastic_body<__hip_bfloat16, __hip_bfloat16>(
            (const __hip_bfloat16*)xin_v, (const __hip_bfloat16*)rdx_v,
            (const __hip_bfloat16*)rdy_v, outp, sdx, sdy);
        else elastic_body<__hip_bfloat16, float>(
            (const float*)xin_v, (const __hip_bfloat16*)rdx_v,
            (const __hip_bfloat16*)rdy_v, outp, sdx, sdy);
    } else {
        if (x_bf) elastic_body<float, __hip_bfloat16>(
            (const __hip_bfloat16*)xin_v, (const float*)rdx_v,
            (const float*)rdy_v, outp, sdx, sdy);
        else elastic_body<float, float>(
            (const float*)xin_v, (const float*)rdx_v,
            (const float*)rdy_v, outp, sdx, sdy);
    }
}

extern "C" void kernel_launch(void* const* d_in, const int* in_sizes, int n_in,
                              void* d_out, int out_size, void* d_ws, size_t ws_size,
                              hipStream_t stream) {
    const void* x   = d_in[0];
    const void* rdx = d_in[1];
    const void* rdy = d_in[2];
    float* out = (float*)d_out;

    const int B = in_sizes[1] / (HEI * WID);   // 64

    dim3 grid(HEI / TY, B);                    // (64, 64) = 4096 blocks
    elastic_kernel<<<grid, 512, 0, stream>>>(x, rdx, rdy, out);
    (void)d_ws; (void)ws_size; (void)n_in; (void)out_size;  // no workspace needed
}

// Round 5
// 283.538 us; speedup vs baseline: 1.2092x; 1.2092x over previous
//
#include <hip/hip_runtime.h>

#define RADIUS 20
#define KSIZE  41
#define ALPHA_F 50.0f
#define TY     8
#define WID    512
#define HEI    512
#define PW     (WID + 2 * RADIUS)   // 552 floats per padded LDS row
#define NR     (TY + 2 * RADIUS)    // 48 input rows per band
#define PF     8                    // phase-1 prefetch depth (rows)

// Normalized Gaussian taps, sigma=5, radius=20: w[t]=exp(-0.5*((t-20)/5)^2)/S,
// S = 12.53263858. Baked literals; fully-unrolled loops fold these to constants.
__device__ constexpr float G[KSIZE] = {
    2.6770e-05f, 5.8390e-05f, 1.22380e-04f, 2.46460e-04f, 4.76840e-04f,
    8.86410e-04f, 1.583160e-03f, 2.716710e-03f, 4.479090e-03f, 7.095210e-03f,
    1.0798630e-02f, 1.5790680e-02f, 2.2185070e-02f, 2.9946720e-02f, 3.8838800e-02f,
    4.8396120e-02f, 5.7940680e-02f, 6.6647650e-02f, 7.3657040e-02f, 7.8211730e-02f,
    7.9791720e-02f,
    7.8211730e-02f, 7.3657040e-02f, 6.6647650e-02f, 5.7940680e-02f, 4.8396120e-02f,
    3.8838800e-02f, 2.9946720e-02f, 2.2185070e-02f, 1.5790680e-02f, 1.0798630e-02f,
    7.095210e-03f, 4.479090e-03f, 2.716710e-03f, 1.583160e-03f, 8.86410e-04f,
    4.76840e-04f, 2.46460e-04f, 1.22380e-04f, 5.8390e-05f, 2.6770e-05f
};

__device__ __forceinline__ int refl(int i, int n) {
    // scipy 'reflect' (edge included); exact for i in [-n, 2n-1]
    i = (i < 0) ? (-1 - i) : i;
    i = (i >= n) ? (2 * n - 1 - i) : i;
    return i;
}
__device__ __forceinline__ int clampi(int i, int n) {
    return (i < 0) ? 0 : ((i >= n) ? n - 1 : i);
}

__global__ __launch_bounds__(512) void elastic_kernel(
    const float* __restrict__ xin, const float* __restrict__ rdx,
    const float* __restrict__ rdy, float* __restrict__ outp, int B) {

    __shared__ float sdx[TY][PW];   // 2 * 8 * 552 * 4 B = 34.5 KB
    __shared__ float sdy[TY][PW];

    const int tid = threadIdx.x;    // 0..511 == column in phase 1

    // Block decode. For B==64: XCD-aware swizzle — consecutive block IDs
    // round-robin across the 8 XCDs, so give each XCD 8 whole batches swept
    // band-by-band: the batch's 2 MB of fields + 1 MB image stay hot in that
    // XCD's 4 MiB L2 across its 64 vertically-overlapping bands.
    int b, band;
    {
        const int L = blockIdx.x;
        if (B == 64) {
            const int xcd = L & 7;
            const int s   = L >> 3;          // 0..511
            b    = xcd * 8 + (s >> 6);       // 8 batches per XCD
            band = s & 63;
        } else {
            b    = L / (HEI / TY);
            band = L % (HEI / TY);
        }
    }
    const int y0 = band * TY;
    const size_t base = (size_t)b * (HEI * WID);

    // ---------------- phase 1: vertical 41-tap blur of (2*r-1) ----------------
    // Accumulator-transposed; rolling PF-row register prefetch so the
    // load->use distance is ~PF rows (compiler emits fine-grained vmcnt waits).
    {
        const float* px = rdx + base + tid;
        const float* py = rdy + base + tid;

        float bx[PF], by[PF];
        #pragma unroll
        for (int k = 0; k < PF; ++k) {
            const int gy = refl(y0 - RADIUS + k, HEI);
            bx[k] = px[(size_t)gy * WID];
            by[k] = py[(size_t)gy * WID];
        }

        float ax[TY], ay[TY];
        #pragma unroll
        for (int o = 0; o < TY; ++o) { ax[o] = 0.f; ay[o] = 0.f; }

        #pragma unroll
        for (int r = 0; r < NR; ++r) {
            const float vx = bx[r & (PF - 1)];   // static index after unroll
            const float vy = by[r & (PF - 1)];
            if (r + PF < NR) {                   // prefetch row r+PF into the slot
                const int gy = refl(y0 - RADIUS + r + PF, HEI);
                bx[r & (PF - 1)] = px[(size_t)gy * WID];
                by[r & (PF - 1)] = py[(size_t)gy * WID];
            }
            #pragma unroll
            for (int o = 0; o < TY; ++o) {
                const int t = r - o;             // static after unroll
                if (t >= 0 && t < KSIZE) {
                    ax[o] = fmaf(G[t], vx, ax[o]);
                    ay[o] = fmaf(G[t], vy, ay[o]);
                }
            }
        }

        #pragma unroll
        for (int o = 0; o < TY; ++o) {
            const float sx = 2.f * ax[o] - 1.f;  // affine commutes with blur (sum G = 1)
            const float sy = 2.f * ay[o] - 1.f;
            sdx[o][RADIUS + tid] = sx;
            sdy[o][RADIUS + tid] = sy;
            if (tid < RADIUS) {                  // col -1-j reflects to col j
                sdx[o][RADIUS - 1 - tid] = sx;
                sdy[o][RADIUS - 1 - tid] = sy;
            }
            if (tid >= WID - RADIUS) {           // col W+j reflects to col W-1-j
                sdx[o][RADIUS + 2 * WID - 1 - tid] = sx;
                sdy[o][RADIUS + 2 * WID - 1 - tid] = sy;
            }
        }
    }
    __syncthreads();

    // ---------- phase 2: horizontal 41-tap blur (*ALPHA) + bilinear warp ----------
    const int c4 = tid & 127;          // float4 index -> cols 4*c4..4*c4+3
    const int rg = tid >> 7;           // 0..3 (wave-uniform)
    const float* img = xin + base;

    #pragma unroll
    for (int i = 0; i < 2; ++i) {
        const int o  = rg + 4 * i;     // rows 0..7
        const int gy = y0 + o;

        float dxv[4] = {0.f, 0.f, 0.f, 0.f};
        float dyv[4] = {0.f, 0.f, 0.f, 0.f};

        {   // 11 aligned float4 LDS reads -> 44-float window, 41-tap FMA x 4 cols
            float w[44];
            const float4* rp = (const float4*)(&sdx[o][0]);
            #pragma unroll
            for (int q = 0; q < 11; ++q) {
                const float4 v = rp[c4 + q];
                w[4 * q + 0] = v.x; w[4 * q + 1] = v.y;
                w[4 * q + 2] = v.z; w[4 * q + 3] = v.w;
            }
            #pragma unroll
            for (int t = 0; t < KSIZE; ++t) {
                const float g = G[t];
                #pragma unroll
                for (int j = 0; j < 4; ++j) dxv[j] = fmaf(g, w[t + j], dxv[j]);
            }
        }
        {
            float w[44];
            const float4* rp = (const float4*)(&sdy[o][0]);
            #pragma unroll
            for (int q = 0; q < 11; ++q) {
                const float4 v = rp[c4 + q];
                w[4 * q + 0] = v.x; w[4 * q + 1] = v.y;
                w[4 * q + 2] = v.z; w[4 * q + 3] = v.w;
            }
            #pragma unroll
            for (int t = 0; t < KSIZE; ++t) {
                const float g = G[t];
                #pragma unroll
                for (int j = 0; j < 4; ++j) dyv[j] = fmaf(g, w[t + j], dyv[j]);
            }
        }

        float st[4];
        #pragma unroll
        for (int j = 0; j < 4; ++j) {
            const int col = 4 * c4 + j;
            float xx = (float)col + dxv[j] * ALPHA_F;
            float yy = (float)gy  + dyv[j] * ALPHA_F;
            // safety clamp: legit range is [-51, 562]; also neutralizes NaN/inf
            xx = fminf(fmaxf(xx, -2048.f), 2048.f);
            yy = fminf(fmaxf(yy, -2048.f), 2048.f);
            const float x0f = floorf(xx), y0f = floorf(yy);
            const float wx = xx - x0f, wy = yy - y0f;
            const int x0 = (int)x0f, yb = (int)y0f;
            const int x0r = clampi(refl(x0, WID), WID);
            const int x1r = clampi(refl(x0 + 1, WID), WID);
            const int y0r = clampi(refl(yb, HEI), HEI);
            const int y1r = clampi(refl(yb + 1, HEI), HEI);

            const float v00 = img[(size_t)y0r * WID + x0r];
            const float v01 = img[(size_t)y0r * WID + x1r];
            const float v10 = img[(size_t)y1r * WID + x0r];
            const float v11 = img[(size_t)y1r * WID + x1r];

            st[j] = v00 * (1.f - wy) * (1.f - wx) + v01 * (1.f - wy) * wx
                  + v10 * wy * (1.f - wx) + v11 * wy * wx;
        }

        float4 pack;
        pack.x = st[0]; pack.y = st[1]; pack.z = st[2]; pack.w = st[3];
        *reinterpret_cast<float4*>(outp + base + (size_t)gy * WID + 4 * c4) = pack;
    }
}

extern "C" void kernel_launch(void* const* d_in, const int* in_sizes, int n_in,
                              void* d_out, int out_size, void* d_ws, size_t ws_size,
                              hipStream_t stream) {
    const float* x   = (const float*)d_in[0];
    const float* rdx = (const float*)d_in[1];
    const float* rdy = (const float*)d_in[2];
    float* out = (float*)d_out;

    const int B = in_sizes[1] / (HEI * WID);   // 64

    const int nblocks = B * (HEI / TY);        // 4096
    elastic_kernel<<<nblocks, 512, 0, stream>>>(x, rdx, rdy, out, B);
    (void)d_ws; (void)ws_size; (void)n_in; (void)out_size;  // no workspace needed
}